// Round 1
// baseline (1008.466 us; speedup 1.0000x reference)
//
#include <hip/hip_runtime.h>
#include <math.h>

#define NN 50000
#define EE 800000
#define HD 128   // H*D
#define BN_EPS 1e-5f

__device__ __forceinline__ unsigned fkey(float f) {
    unsigned b = __float_as_uint(f);
    return (b & 0x80000000u) ? ~b : (b | 0x80000000u);
}
__device__ __forceinline__ float funkey(unsigned k) {
    unsigned b = (k & 0x80000000u) ? (k ^ 0x80000000u) : ~k;
    return __uint_as_float(b);
}

// ---- Phase 1: Q,K,V,S = x @ {Wq,Wk,Wv,Wskip} + bias ----------------------
// 16 rows x 512 cols per block. x tile in LDS (wave-uniform broadcast reads),
// W streamed from global (256KB total -> L2 hot). Each thread: 2 cols x 16 rows.
__global__ __launch_bounds__(256) void gemm_qkvs(
    const float* __restrict__ x,
    const float* __restrict__ Wq, const float* __restrict__ bq,
    const float* __restrict__ Wk, const float* __restrict__ bk,
    const float* __restrict__ Wv, const float* __restrict__ bv,
    const float* __restrict__ Ws, const float* __restrict__ bs,
    float* __restrict__ Q, float* __restrict__ K,
    float* __restrict__ V, float* __restrict__ S)
{
    __shared__ __align__(16) float xs[16][128];
    int t = threadIdx.x;
    int row0 = blockIdx.x * 16;           // NN % 16 == 0
    #pragma unroll
    for (int i = 0; i < 2; ++i) {
        int fi = t + i * 256;             // float4 index into tile
        ((float4*)xs)[fi] = ((const float4*)x)[row0 * 32 + fi];
    }
    __syncthreads();

    int col = t & 127;
    bool lo = (t < 128);
    const float* W0 = lo ? Wq : Wk;       // j0 = t       in [0,256)
    const float* W1 = lo ? Wv : Ws;       // j1 = t + 256 in [256,512)
    float b0 = (lo ? bq : bk)[col];
    float b1 = (lo ? bv : bs)[col];

    float acc0[16], acc1[16];
    #pragma unroll
    for (int r = 0; r < 16; ++r) { acc0[r] = 0.f; acc1[r] = 0.f; }

    for (int k = 0; k < 128; k += 4) {
        float w00 = W0[(k+0)*128+col], w01 = W0[(k+1)*128+col];
        float w02 = W0[(k+2)*128+col], w03 = W0[(k+3)*128+col];
        float w10 = W1[(k+0)*128+col], w11 = W1[(k+1)*128+col];
        float w12 = W1[(k+2)*128+col], w13 = W1[(k+3)*128+col];
        #pragma unroll
        for (int r = 0; r < 16; ++r) {
            float4 xv = *(const float4*)&xs[r][k];
            acc0[r] = fmaf(xv.w, w03, fmaf(xv.z, w02, fmaf(xv.y, w01, fmaf(xv.x, w00, acc0[r]))));
            acc1[r] = fmaf(xv.w, w13, fmaf(xv.z, w12, fmaf(xv.y, w11, fmaf(xv.x, w10, acc1[r]))));
        }
    }
    float* D0 = lo ? Q : K;
    float* D1 = lo ? V : S;
    #pragma unroll
    for (int r = 0; r < 16; ++r) {
        D0[(row0 + r) * HD + col] = acc0[r] + b0;
        D1[(row0 + r) * HD + col] = acc1[r] + b1;
    }
}

// ---- Phase 2: per-edge logits + segment max ------------------------------
// one wave per (edge, head): lane d covers dim d; coalesced 256B row reads.
__global__ __launch_bounds__(256) void edge_logits_kernel(
    const float* __restrict__ Q, const float* __restrict__ K,
    const int* __restrict__ ei,
    float* __restrict__ logits, unsigned* __restrict__ maxkey)
{
    int t = threadIdx.x;
    int e = blockIdx.x * 2 + (t >> 7);
    int h = (t >> 6) & 1;
    int d = t & 63;
    int src = ei[e];
    int dst = ei[EE + e];
    float p = Q[dst * HD + h * 64 + d] * K[src * HD + h * 64 + d];
    #pragma unroll
    for (int off = 32; off > 0; off >>= 1)
        p += __shfl_xor(p, off, 64);
    if (d == 0) {
        float logit = p * 0.125f;   // / sqrt(64)
        logits[e * 2 + h] = logit;
        atomicMax(&maxkey[dst * 2 + h], fkey(logit));
    }
}

// ---- Phase 3: ex = exp(logit - max); scatter ex*v and ex (denom) ---------
__global__ __launch_bounds__(256) void edge_scatter_kernel(
    const float* __restrict__ V, const float* __restrict__ logits,
    const unsigned* __restrict__ maxkey, float* __restrict__ denom,
    float* __restrict__ accum, const int* __restrict__ ei)
{
    int t = threadIdx.x;
    int e = blockIdx.x * 2 + (t >> 7);
    int h = (t >> 6) & 1;
    int d = t & 63;
    int src = ei[e];
    int dst = ei[EE + e];
    unsigned key = maxkey[dst * 2 + h];
    float m = (key == 0u) ? 0.f : funkey(key);
    float ex = expf(logits[e * 2 + h] - m);
    if (d == 0) atomicAdd(&denom[dst * 2 + h], ex);
    float vv = V[src * HD + h * 64 + d];
    atomicAdd(&accum[dst * HD + h * 64 + d], ex * vv);
}

// ---- Phase 4: out = accum/denom + skip; column sums for BN ---------------
__global__ __launch_bounds__(256) void finalize_kernel(
    float* __restrict__ accum, const float* __restrict__ denom,
    const float* __restrict__ S,
    float* __restrict__ colsum, float* __restrict__ colsq)
{
    __shared__ float ssum[256], ssq[256];
    int t = threadIdx.x;
    int c = t & 127;
    int sub = t >> 7;
    int n0 = blockIdx.x * 64;
    float ls = 0.f, lq = 0.f;
    for (int r = sub; r < 64; r += 2) {
        int n = n0 + r;
        if (n < NN) {
            float den = fmaxf(denom[n * 2 + (c >> 6)], 1e-16f);
            float val = accum[n * HD + c] / den + S[n * HD + c];
            accum[n * HD + c] = val;
            ls += val; lq += val * val;
        }
    }
    ssum[t] = ls; ssq[t] = lq;
    __syncthreads();
    if (sub == 0) {
        atomicAdd(&colsum[c], ssum[t] + ssum[t + 128]);
        atomicAdd(&colsq[c],  ssq[t]  + ssq[t + 128]);
    }
}

// ---- Phase 5: BatchNorm (batch stats, biased var) + Mish, in place -------
__global__ __launch_bounds__(256) void bn_mish_kernel(
    float* __restrict__ y, const float* __restrict__ colsum,
    const float* __restrict__ colsq,
    const float* __restrict__ gamma, const float* __restrict__ beta)
{
    int i = blockIdx.x * 256 + threadIdx.x;
    if (i >= NN * HD) return;
    int c = i & 127;
    const float invN = 1.0f / (float)NN;
    float mean = colsum[c] * invN;
    float var  = colsq[c] * invN - mean * mean;
    float v = y[i];
    float yn = gamma[c] * (v - mean) * rsqrtf(var + BN_EPS) + beta[c];
    float sp = (yn > 20.f) ? yn : log1pf(expf(yn));
    y[i] = yn * tanhf(sp);
}

extern "C" void kernel_launch(void* const* d_in, const int* in_sizes, int n_in,
                              void* d_out, int out_size, void* d_ws, size_t ws_size,
                              hipStream_t stream) {
    const float* x     = (const float*)d_in[0];
    const int*   ei    = (const int*)d_in[1];
    const float* Wq    = (const float*)d_in[2];
    const float* bq    = (const float*)d_in[3];
    const float* Wk    = (const float*)d_in[4];
    const float* bk    = (const float*)d_in[5];
    const float* Wv    = (const float*)d_in[6];
    const float* bv    = (const float*)d_in[7];
    const float* Wsk   = (const float*)d_in[8];
    const float* bsk   = (const float*)d_in[9];
    const float* gamma = (const float*)d_in[10];
    const float* beta  = (const float*)d_in[11];
    float* out = (float*)d_out;

    float* ws = (float*)d_ws;
    float* Q      = ws;                          // N*128
    float* K      = Q + (size_t)NN * HD;         // N*128
    float* V      = K + (size_t)NN * HD;         // N*128
    float* S      = V + (size_t)NN * HD;         // N*128
    float* logits = S + (size_t)NN * HD;         // E*2
    unsigned* maxkey = (unsigned*)(logits + (size_t)EE * 2);  // N*2
    float* denom  = (float*)(maxkey + (size_t)NN * 2);        // N*2
    float* colsum = denom + (size_t)NN * 2;      // 128
    float* colsq  = colsum + HD;                 // 128

    hipMemsetAsync(out,    0, (size_t)NN * HD * sizeof(float), stream);
    hipMemsetAsync(maxkey, 0, (size_t)NN * 2 * sizeof(unsigned), stream);
    hipMemsetAsync(denom,  0, (size_t)NN * 2 * sizeof(float), stream);
    hipMemsetAsync(colsum, 0, 2 * HD * sizeof(float), stream);

    gemm_qkvs<<<NN / 16, 256, 0, stream>>>(x, Wq, bq, Wk, bk, Wv, bv, Wsk, bsk,
                                           Q, K, V, S);
    edge_logits_kernel<<<EE / 2, 256, 0, stream>>>(Q, K, ei, logits, maxkey);
    edge_scatter_kernel<<<EE / 2, 256, 0, stream>>>(V, logits, maxkey, denom, out, ei);
    finalize_kernel<<<(NN + 63) / 64, 256, 0, stream>>>(out, denom, S, colsum, colsq);
    bn_mish_kernel<<<(NN * HD + 255) / 256, 256, 0, stream>>>(out, colsum, colsq, gamma, beta);
}

// Round 2
// 548.982 us; speedup vs baseline: 1.8370x; 1.8370x over previous
//
#include <hip/hip_runtime.h>
#include <math.h>

#define NN 50000
#define EE 800000
#define HD 128   // H*D
#define BN_EPS 1e-5f

// ---- Phase 1: Q,K,V,S = x @ {Wq,Wk,Wv,Wskip} + bias ----------------------
__global__ __launch_bounds__(256) void gemm_qkvs(
    const float* __restrict__ x,
    const float* __restrict__ Wq, const float* __restrict__ bq,
    const float* __restrict__ Wk, const float* __restrict__ bk,
    const float* __restrict__ Wv, const float* __restrict__ bv,
    const float* __restrict__ Ws, const float* __restrict__ bs,
    float* __restrict__ Q, float* __restrict__ K,
    float* __restrict__ V, float* __restrict__ S)
{
    __shared__ __align__(16) float xs[16][128];
    int t = threadIdx.x;
    int row0 = blockIdx.x * 16;           // NN % 16 == 0
    #pragma unroll
    for (int i = 0; i < 2; ++i) {
        int fi = t + i * 256;             // float4 index into tile
        ((float4*)xs)[fi] = ((const float4*)x)[row0 * 32 + fi];
    }
    __syncthreads();

    int col = t & 127;
    bool lo = (t < 128);
    const float* W0 = lo ? Wq : Wk;
    const float* W1 = lo ? Wv : Ws;
    float b0 = (lo ? bq : bk)[col];
    float b1 = (lo ? bv : bs)[col];

    float acc0[16], acc1[16];
    #pragma unroll
    for (int r = 0; r < 16; ++r) { acc0[r] = 0.f; acc1[r] = 0.f; }

    for (int k = 0; k < 128; k += 4) {
        float w00 = W0[(k+0)*128+col], w01 = W0[(k+1)*128+col];
        float w02 = W0[(k+2)*128+col], w03 = W0[(k+3)*128+col];
        float w10 = W1[(k+0)*128+col], w11 = W1[(k+1)*128+col];
        float w12 = W1[(k+2)*128+col], w13 = W1[(k+3)*128+col];
        #pragma unroll
        for (int r = 0; r < 16; ++r) {
            float4 xv = *(const float4*)&xs[r][k];
            acc0[r] = fmaf(xv.w, w03, fmaf(xv.z, w02, fmaf(xv.y, w01, fmaf(xv.x, w00, acc0[r]))));
            acc1[r] = fmaf(xv.w, w13, fmaf(xv.z, w12, fmaf(xv.y, w11, fmaf(xv.x, w10, acc1[r]))));
        }
    }
    float* D0 = lo ? Q : K;
    float* D1 = lo ? V : S;
    #pragma unroll
    for (int r = 0; r < 16; ++r) {
        D0[(row0 + r) * HD + col] = acc0[r] + b0;
        D1[(row0 + r) * HD + col] = acc1[r] + b1;
    }
}

// ---- CSR build: histogram of dst degrees ---------------------------------
__global__ __launch_bounds__(256) void hist_kernel(
    const int* __restrict__ ei, int* __restrict__ deg)
{
    int e = blockIdx.x * 256 + threadIdx.x;   // EE % 256 == 0
    atomicAdd(&deg[ei[EE + e]], 1);
}

// ---- CSR build: hierarchical exclusive scan ------------------------------
// scan1: per-block (256) exclusive scan, emit block totals
__global__ __launch_bounds__(256) void scan1_kernel(
    const int* __restrict__ deg, int* __restrict__ rowptr,
    int* __restrict__ blocksum)
{
    __shared__ int s[256];
    int t = threadIdx.x;
    int g = blockIdx.x * 256 + t;
    int v = (g < NN) ? deg[g] : 0;
    s[t] = v;
    __syncthreads();
    #pragma unroll
    for (int off = 1; off < 256; off <<= 1) {
        int tmp = (t >= off) ? s[t - off] : 0;
        __syncthreads();
        s[t] += tmp;
        __syncthreads();
    }
    if (g < NN) rowptr[g] = s[t] - v;   // exclusive
    if (t == 255) blocksum[blockIdx.x] = s[255];
}

// scan2: single block scans the block totals (exclusive), in place
__global__ __launch_bounds__(256) void scan2_kernel(int* __restrict__ blocksum, int nb)
{
    __shared__ int s[256];
    int t = threadIdx.x;
    int v = (t < nb) ? blocksum[t] : 0;
    s[t] = v;
    __syncthreads();
    #pragma unroll
    for (int off = 1; off < 256; off <<= 1) {
        int tmp = (t >= off) ? s[t - off] : 0;
        __syncthreads();
        s[t] += tmp;
        __syncthreads();
    }
    if (t < nb) blocksum[t] = s[t] - v;   // exclusive
}

// scan3: add block offsets
__global__ __launch_bounds__(256) void scan3_kernel(
    int* __restrict__ rowptr, const int* __restrict__ blocksum)
{
    int g = blockIdx.x * 256 + threadIdx.x;
    if (g < NN) rowptr[g] += blocksum[blockIdx.x];
}

// ---- CSR build: scatter src ids grouped by dst ---------------------------
__global__ __launch_bounds__(256) void csr_scatter_kernel(
    const int* __restrict__ ei, const int* __restrict__ rowptr,
    int* __restrict__ cursor, int* __restrict__ sortedSrc)
{
    int e = blockIdx.x * 256 + threadIdx.x;   // EE % 256 == 0
    int dst = ei[EE + e];
    int pos = atomicAdd(&cursor[dst], 1);
    sortedSrc[rowptr[dst] + pos] = ei[e];
}

// ---- Fused attention: one wave per (dst, head), online softmax -----------
// No atomics; writes out = acc/denom + skip directly.
__global__ __launch_bounds__(256) void attn_fused_kernel(
    const float* __restrict__ Q, const float* __restrict__ K,
    const float* __restrict__ V, const float* __restrict__ S,
    const int* __restrict__ rowptr, const int* __restrict__ deg,
    const int* __restrict__ sortedSrc, float* __restrict__ out)
{
    int t = threadIdx.x;
    int wave = t >> 6;
    int lane = t & 63;
    int dst = blockIdx.x * 2 + (wave >> 1);
    int h = wave & 1;
    if (dst >= NN) return;

    int base = rowptr[dst];
    int cnt  = deg[dst];
    int off  = h * 64 + lane;

    float q = Q[dst * HD + off];
    float m = -1e30f, den = 0.f, acc = 0.f;

    int   src  = (cnt > 0) ? sortedSrc[base] : 0;
    float kreg = 0.f, vreg = 0.f;
    if (cnt > 0) { kreg = K[src * HD + off]; vreg = V[src * HD + off]; }

    for (int i = 0; i < cnt; ++i) {
        // prefetch next edge
        float nk = 0.f, nv = 0.f;
        if (i + 1 < cnt) {
            int nsrc = sortedSrc[base + i + 1];
            nk = K[nsrc * HD + off];
            nv = V[nsrc * HD + off];
        }
        float p = q * kreg;
        #pragma unroll
        for (int o = 32; o > 0; o >>= 1)
            p += __shfl_xor(p, o, 64);
        float logit = p * 0.125f;             // / sqrt(64)
        float mnew  = fmaxf(m, logit);
        float scale = __expf(m - mnew);
        float w     = __expf(logit - mnew);
        acc = acc * scale + w * vreg;
        den = den * scale + w;
        m = mnew;
        kreg = nk; vreg = nv;
    }
    out[dst * HD + off] = acc / fmaxf(den, 1e-16f) + S[dst * HD + off];
}

// ---- Column stats for BN: colsum / colsq over out ------------------------
__global__ __launch_bounds__(256) void colstats_kernel(
    const float* __restrict__ out,
    float* __restrict__ colsum, float* __restrict__ colsq)
{
    __shared__ float ssum[256], ssq[256];
    int t = threadIdx.x;
    int c = t & 127;
    int sub = t >> 7;
    int n0 = blockIdx.x * 64;
    float ls = 0.f, lq = 0.f;
    for (int r = sub; r < 64; r += 2) {
        int n = n0 + r;
        if (n < NN) {
            float v = out[n * HD + c];
            ls += v; lq += v * v;
        }
    }
    ssum[t] = ls; ssq[t] = lq;
    __syncthreads();
    if (sub == 0) {
        atomicAdd(&colsum[c], ssum[t] + ssum[t + 128]);
        atomicAdd(&colsq[c],  ssq[t]  + ssq[t + 128]);
    }
}

// ---- BatchNorm (batch stats, biased var) + Mish, in place ----------------
__global__ __launch_bounds__(256) void bn_mish_kernel(
    float* __restrict__ y, const float* __restrict__ colsum,
    const float* __restrict__ colsq,
    const float* __restrict__ gamma, const float* __restrict__ beta)
{
    int i = blockIdx.x * 256 + threadIdx.x;
    if (i >= NN * HD) return;
    int c = i & 127;
    const float invN = 1.0f / (float)NN;
    float mean = colsum[c] * invN;
    float var  = colsq[c] * invN - mean * mean;
    float v = y[i];
    float yn = gamma[c] * (v - mean) * rsqrtf(var + BN_EPS) + beta[c];
    float sp = (yn > 20.f) ? yn : log1pf(expf(yn));
    y[i] = yn * tanhf(sp);
}

extern "C" void kernel_launch(void* const* d_in, const int* in_sizes, int n_in,
                              void* d_out, int out_size, void* d_ws, size_t ws_size,
                              hipStream_t stream) {
    const float* x     = (const float*)d_in[0];
    const int*   ei    = (const int*)d_in[1];
    const float* Wq    = (const float*)d_in[2];
    const float* bq    = (const float*)d_in[3];
    const float* Wk    = (const float*)d_in[4];
    const float* bk    = (const float*)d_in[5];
    const float* Wv    = (const float*)d_in[6];
    const float* bv    = (const float*)d_in[7];
    const float* Wsk   = (const float*)d_in[8];
    const float* bsk   = (const float*)d_in[9];
    const float* gamma = (const float*)d_in[10];
    const float* beta  = (const float*)d_in[11];
    float* out = (float*)d_out;

    float* ws = (float*)d_ws;
    float* Q = ws;                           // N*128
    float* K = Q + (size_t)NN * HD;          // N*128
    float* V = K + (size_t)NN * HD;          // N*128
    float* S = V + (size_t)NN * HD;          // N*128
    int* deg       = (int*)(S + (size_t)NN * HD);  // N
    int* rowptr    = deg + NN;               // N
    int* cursor    = rowptr + NN;            // N
    int* blocksum  = cursor + NN;            // 256
    int* sortedSrc = blocksum + 256;         // E
    float* colsum  = (float*)(sortedSrc + EE);  // 128
    float* colsq   = colsum + HD;            // 128

    const int NB1 = (NN + 255) / 256;        // 196 scan blocks

    hipMemsetAsync(deg,    0, NN * sizeof(int), stream);
    hipMemsetAsync(cursor, 0, NN * sizeof(int), stream);
    hipMemsetAsync(colsum, 0, 2 * HD * sizeof(float), stream);

    gemm_qkvs<<<NN / 16, 256, 0, stream>>>(x, Wq, bq, Wk, bk, Wv, bv, Wsk, bsk,
                                           Q, K, V, S);
    hist_kernel<<<EE / 256, 256, 0, stream>>>(ei, deg);
    scan1_kernel<<<NB1, 256, 0, stream>>>(deg, rowptr, blocksum);
    scan2_kernel<<<1, 256, 0, stream>>>(blocksum, NB1);
    scan3_kernel<<<NB1, 256, 0, stream>>>(rowptr, blocksum);
    csr_scatter_kernel<<<EE / 256, 256, 0, stream>>>(ei, rowptr, cursor, sortedSrc);
    attn_fused_kernel<<<(NN + 1) / 2, 256, 0, stream>>>(Q, K, V, S, rowptr, deg,
                                                        sortedSrc, out);
    colstats_kernel<<<(NN + 63) / 64, 256, 0, stream>>>(out, colsum, colsq);
    bn_mish_kernel<<<(NN * HD + 255) / 256, 256, 0, stream>>>(out, colsum, colsq,
                                                              gamma, beta);
}

// Round 3
// 435.091 us; speedup vs baseline: 2.3178x; 1.2618x over previous
//
#include <hip/hip_runtime.h>
#include <hip/hip_bf16.h>
#include <math.h>

#define NN 50000
#define EE 800000
#define HD 128   // H*D
#define BN_EPS 1e-5f

__device__ __forceinline__ unsigned short f2bf(float f) {
    // round-to-nearest-even bf16
    unsigned u = __float_as_uint(f);
    unsigned rounded = u + 0x7fffu + ((u >> 16) & 1u);
    return (unsigned short)(rounded >> 16);
}

// ---- Phase 1: Q,K,V,S = x @ {Wq,Wk,Wv,Wskip} + bias ----------------------
// Q,S stored fp32; K,V stored bf16 (halves attention gather traffic).
__global__ __launch_bounds__(256) void gemm_qkvs(
    const float* __restrict__ x,
    const float* __restrict__ Wq, const float* __restrict__ bq,
    const float* __restrict__ Wk, const float* __restrict__ bk,
    const float* __restrict__ Wv, const float* __restrict__ bv,
    const float* __restrict__ Ws, const float* __restrict__ bs,
    float* __restrict__ Q, unsigned short* __restrict__ Kh,
    unsigned short* __restrict__ Vh, float* __restrict__ S)
{
    __shared__ __align__(16) float xs[16][128];
    int t = threadIdx.x;
    int row0 = blockIdx.x * 16;           // NN % 16 == 0
    #pragma unroll
    for (int i = 0; i < 2; ++i) {
        int fi = t + i * 256;             // float4 index into tile
        ((float4*)xs)[fi] = ((const float4*)x)[row0 * 32 + fi];
    }
    __syncthreads();

    int col = t & 127;
    bool lo = (t < 128);
    const float* W0 = lo ? Wq : Wk;
    const float* W1 = lo ? Wv : Ws;
    float b0 = (lo ? bq : bk)[col];
    float b1 = (lo ? bv : bs)[col];

    float acc0[16], acc1[16];
    #pragma unroll
    for (int r = 0; r < 16; ++r) { acc0[r] = 0.f; acc1[r] = 0.f; }

    for (int k = 0; k < 128; k += 4) {
        float w00 = W0[(k+0)*128+col], w01 = W0[(k+1)*128+col];
        float w02 = W0[(k+2)*128+col], w03 = W0[(k+3)*128+col];
        float w10 = W1[(k+0)*128+col], w11 = W1[(k+1)*128+col];
        float w12 = W1[(k+2)*128+col], w13 = W1[(k+3)*128+col];
        #pragma unroll
        for (int r = 0; r < 16; ++r) {
            float4 xv = *(const float4*)&xs[r][k];
            acc0[r] = fmaf(xv.w, w03, fmaf(xv.z, w02, fmaf(xv.y, w01, fmaf(xv.x, w00, acc0[r]))));
            acc1[r] = fmaf(xv.w, w13, fmaf(xv.z, w12, fmaf(xv.y, w11, fmaf(xv.x, w10, acc1[r]))));
        }
    }
    if (lo) {
        #pragma unroll
        for (int r = 0; r < 16; ++r) {
            Q [(row0 + r) * HD + col] = acc0[r] + b0;
            Vh[(row0 + r) * HD + col] = f2bf(acc1[r] + b1);
        }
    } else {
        #pragma unroll
        for (int r = 0; r < 16; ++r) {
            Kh[(row0 + r) * HD + col] = f2bf(acc0[r] + b0);
            S [(row0 + r) * HD + col] = acc1[r] + b1;
        }
    }
}

// ---- CSR build: histogram of dst degrees ---------------------------------
__global__ __launch_bounds__(256) void hist_kernel(
    const int* __restrict__ ei, int* __restrict__ deg)
{
    int e = blockIdx.x * 256 + threadIdx.x;   // EE % 256 == 0
    atomicAdd(&deg[ei[EE + e]], 1);
}

// scan1: per-block (256) exclusive scan, emit block totals
__global__ __launch_bounds__(256) void scan1_kernel(
    const int* __restrict__ deg, int* __restrict__ rowptr,
    int* __restrict__ blocksum)
{
    __shared__ int s[256];
    int t = threadIdx.x;
    int g = blockIdx.x * 256 + t;
    int v = (g < NN) ? deg[g] : 0;
    s[t] = v;
    __syncthreads();
    #pragma unroll
    for (int off = 1; off < 256; off <<= 1) {
        int tmp = (t >= off) ? s[t - off] : 0;
        __syncthreads();
        s[t] += tmp;
        __syncthreads();
    }
    if (g < NN) rowptr[g] = s[t] - v;   // exclusive
    if (t == 255) blocksum[blockIdx.x] = s[255];
}

// scan2: single block scans block totals (exclusive), in place
__global__ __launch_bounds__(256) void scan2_kernel(int* __restrict__ blocksum, int nb)
{
    __shared__ int s[256];
    int t = threadIdx.x;
    int v = (t < nb) ? blocksum[t] : 0;
    s[t] = v;
    __syncthreads();
    #pragma unroll
    for (int off = 1; off < 256; off <<= 1) {
        int tmp = (t >= off) ? s[t - off] : 0;
        __syncthreads();
        s[t] += tmp;
        __syncthreads();
    }
    if (t < nb) blocksum[t] = s[t] - v;   // exclusive
}

// scan3: add block offsets
__global__ __launch_bounds__(256) void scan3_kernel(
    int* __restrict__ rowptr, const int* __restrict__ blocksum)
{
    int g = blockIdx.x * 256 + threadIdx.x;
    if (g < NN) rowptr[g] += blocksum[blockIdx.x];
}

// ---- CSR build: scatter src ids grouped by dst ---------------------------
__global__ __launch_bounds__(256) void csr_scatter_kernel(
    const int* __restrict__ ei, const int* __restrict__ rowptr,
    int* __restrict__ cursor, int* __restrict__ sortedSrc)
{
    int e = blockIdx.x * 256 + threadIdx.x;   // EE % 256 == 0
    int dst = ei[EE + e];
    int pos = atomicAdd(&cursor[dst], 1);
    sortedSrc[rowptr[dst] + pos] = ei[e];
}

// ---- Fused attention: one wave per dst (both heads), online softmax ------
// Lane covers dims {2*lane, 2*lane+1}; lanes 0-31 = head0, 32-63 = head1.
// K/V rows are bf16-packed: one uint load per lane = full 256B row per wave.
__global__ __launch_bounds__(256) void attn_fused_kernel(
    const float* __restrict__ Q, const unsigned* __restrict__ Kp,
    const unsigned* __restrict__ Vp, const float* __restrict__ S,
    const int* __restrict__ rowptr, const int* __restrict__ deg,
    const int* __restrict__ sortedSrc, float* __restrict__ out)
{
    int t = threadIdx.x;
    int wave = t >> 6;
    int lane = t & 63;
    int dst = blockIdx.x * 4 + wave;      // NN % 4 == 0
    if (dst >= NN) return;

    int base = rowptr[dst];
    int cnt  = deg[dst];

    float2 q = ((const float2*)Q)[dst * 64 + lane];
    float m = -1e30f, den = 0.f, a0 = 0.f, a1 = 0.f;

    for (int c0 = 0; c0 < cnt; c0 += 64) {
        int nload = cnt - c0; if (nload > 64) nload = 64;
        int sidx = sortedSrc[base + c0 + ((lane < nload) ? lane : (nload - 1))];
        int src0 = __shfl(sidx, 0, 64);
        unsigned ku = Kp[src0 * 64 + lane];
        unsigned vu = Vp[src0 * 64 + lane];
        for (int i = 0; i < nload; ++i) {
            unsigned nku = 0, nvu = 0;
            if (i + 1 < nload) {
                int ns = __shfl(sidx, i + 1, 64);
                nku = Kp[ns * 64 + lane];
                nvu = Vp[ns * 64 + lane];
            }
            float k0 = __uint_as_float(ku << 16);
            float k1 = __uint_as_float(ku & 0xffff0000u);
            float v0 = __uint_as_float(vu << 16);
            float v1 = __uint_as_float(vu & 0xffff0000u);
            float p = fmaf(q.x, k0, q.y * k1);
            #pragma unroll
            for (int o = 16; o > 0; o >>= 1)     // reduces within each 32-half
                p += __shfl_xor(p, o, 64);
            float logit = p * 0.125f;            // / sqrt(64)
            float mnew  = fmaxf(m, logit);
            float sc    = __expf(m - mnew);
            float w     = __expf(logit - mnew);
            a0 = a0 * sc + w * v0;
            a1 = a1 * sc + w * v1;
            den = den * sc + w;
            m = mnew;
            ku = nku; vu = nvu;
        }
    }
    float inv = 1.0f / fmaxf(den, 1e-16f);
    float2 sk = ((const float2*)S)[dst * 64 + lane];
    float2 o2;
    o2.x = a0 * inv + sk.x;
    o2.y = a1 * inv + sk.y;
    ((float2*)out)[dst * 64 + lane] = o2;
}

// ---- Column stats for BN ------------------------------------------------
__global__ __launch_bounds__(256) void colstats_kernel(
    const float* __restrict__ out,
    float* __restrict__ colsum, float* __restrict__ colsq)
{
    __shared__ float ssum[256], ssq[256];
    int t = threadIdx.x;
    int c = t & 127;
    int sub = t >> 7;
    int n0 = blockIdx.x * 64;
    float ls = 0.f, lq = 0.f;
    for (int r = sub; r < 64; r += 2) {
        int n = n0 + r;
        if (n < NN) {
            float v = out[n * HD + c];
            ls += v; lq += v * v;
        }
    }
    ssum[t] = ls; ssq[t] = lq;
    __syncthreads();
    if (sub == 0) {
        atomicAdd(&colsum[c], ssum[t] + ssum[t + 128]);
        atomicAdd(&colsq[c],  ssq[t]  + ssq[t + 128]);
    }
}

// ---- BatchNorm (batch stats, biased var) + Mish, in place ----------------
__global__ __launch_bounds__(256) void bn_mish_kernel(
    float* __restrict__ y, const float* __restrict__ colsum,
    const float* __restrict__ colsq,
    const float* __restrict__ gamma, const float* __restrict__ beta)
{
    int i = blockIdx.x * 256 + threadIdx.x;
    if (i >= NN * HD) return;
    int c = i & 127;
    const float invN = 1.0f / (float)NN;
    float mean = colsum[c] * invN;
    float var  = colsq[c] * invN - mean * mean;
    float v = y[i];
    float yn = gamma[c] * (v - mean) * rsqrtf(var + BN_EPS) + beta[c];
    float sp = (yn > 20.f) ? yn : log1pf(expf(yn));
    y[i] = yn * tanhf(sp);
}

extern "C" void kernel_launch(void* const* d_in, const int* in_sizes, int n_in,
                              void* d_out, int out_size, void* d_ws, size_t ws_size,
                              hipStream_t stream) {
    const float* x     = (const float*)d_in[0];
    const int*   ei    = (const int*)d_in[1];
    const float* Wq    = (const float*)d_in[2];
    const float* bq    = (const float*)d_in[3];
    const float* Wk    = (const float*)d_in[4];
    const float* bk    = (const float*)d_in[5];
    const float* Wv    = (const float*)d_in[6];
    const float* bv    = (const float*)d_in[7];
    const float* Wsk   = (const float*)d_in[8];
    const float* bsk   = (const float*)d_in[9];
    const float* gamma = (const float*)d_in[10];
    const float* beta  = (const float*)d_in[11];
    float* out = (float*)d_out;

    char* ws = (char*)d_ws;
    float* Q  = (float*)ws;                       ws += (size_t)NN * HD * 4;
    float* S  = (float*)ws;                       ws += (size_t)NN * HD * 4;
    unsigned short* Kh = (unsigned short*)ws;     ws += (size_t)NN * HD * 2;
    unsigned short* Vh = (unsigned short*)ws;     ws += (size_t)NN * HD * 2;
    int* deg       = (int*)ws;                    ws += (size_t)NN * 4;
    int* rowptr    = (int*)ws;                    ws += (size_t)NN * 4;
    int* cursor    = (int*)ws;                    ws += (size_t)NN * 4;
    int* blocksum  = (int*)ws;                    ws += 256 * 4;
    int* sortedSrc = (int*)ws;                    ws += (size_t)EE * 4;
    float* colsum  = (float*)ws;                  ws += HD * 4;
    float* colsq   = (float*)ws;

    const int NB1 = (NN + 255) / 256;

    hipMemsetAsync(deg,    0, NN * sizeof(int), stream);
    hipMemsetAsync(cursor, 0, NN * sizeof(int), stream);
    hipMemsetAsync(colsum, 0, 2 * HD * sizeof(float), stream);

    gemm_qkvs<<<NN / 16, 256, 0, stream>>>(x, Wq, bq, Wk, bk, Wv, bv, Wsk, bsk,
                                           Q, Kh, Vh, S);
    hist_kernel<<<EE / 256, 256, 0, stream>>>(ei, deg);
    scan1_kernel<<<NB1, 256, 0, stream>>>(deg, rowptr, blocksum);
    scan2_kernel<<<1, 256, 0, stream>>>(blocksum, NB1);
    scan3_kernel<<<NB1, 256, 0, stream>>>(rowptr, blocksum);
    csr_scatter_kernel<<<EE / 256, 256, 0, stream>>>(ei, rowptr, cursor, sortedSrc);
    attn_fused_kernel<<<NN / 4, 256, 0, stream>>>(Q, (const unsigned*)Kh,
                                                  (const unsigned*)Vh, S,
                                                  rowptr, deg, sortedSrc, out);
    colstats_kernel<<<(NN + 63) / 64, 256, 0, stream>>>(out, colsum, colsq);
    bn_mish_kernel<<<(NN * HD + 255) / 256, 256, 0, stream>>>(out, colsum, colsq,
                                                              gamma, beta);
}

// Round 4
// 371.209 us; speedup vs baseline: 2.7167x; 1.1721x over previous
//
#include <hip/hip_runtime.h>
#include <hip/hip_bf16.h>
#include <math.h>

#define NN 50000
#define EE 800000
#define HD 128   // H*D
#define BN_EPS 1e-5f

typedef __attribute__((ext_vector_type(8))) short bf16x8;
typedef __attribute__((ext_vector_type(4))) float f32x4;

__device__ __forceinline__ unsigned short f2bf(float f) {
    // round-to-nearest-even bf16
    unsigned u = __float_as_uint(f);
    unsigned rounded = u + 0x7fffu + ((u >> 16) & 1u);
    return (unsigned short)(rounded >> 16);
}

// ---- Prep: Wt[n][k] = bf16(W_{n/128}[k][n%128]) ; n in [0,512) ----------
__global__ __launch_bounds__(256) void wcast_kernel(
    const float* __restrict__ Wq, const float* __restrict__ Wk,
    const float* __restrict__ Wv, const float* __restrict__ Ws,
    unsigned short* __restrict__ Wt)
{
    int i = blockIdx.x * 256 + threadIdx.x;   // 65536 total
    int n = i >> 7;
    int k = i & 127;
    const float* W = (n < 128) ? Wq : (n < 256) ? Wk : (n < 384) ? Wv : Ws;
    Wt[n * 128 + k] = f2bf(W[k * 128 + (n & 127)]);
}

// ---- Phase 1: MFMA GEMM. Block = 32 rows x 512 cols; wave w owns matrix w.
// Q,S stored fp32; K,V stored bf16.
__global__ __launch_bounds__(256) void gemm_mfma(
    const float* __restrict__ x, const unsigned short* __restrict__ Wt,
    const float* __restrict__ bq, const float* __restrict__ bk,
    const float* __restrict__ bv, const float* __restrict__ bs,
    float* __restrict__ Q, unsigned short* __restrict__ Kh,
    unsigned short* __restrict__ Vh, float* __restrict__ S)
{
    // row stride 136 bf16 = 272B: 16B-aligned, breaks 16-way bank aliasing
    __shared__ __align__(16) unsigned short xs[32 * 136];
    int t = threadIdx.x;
    int row0 = blockIdx.x * 32;

    // stage + cast x tile (32x128 fp32 -> bf16 LDS)
    #pragma unroll
    for (int it = 0; it < 2; ++it) {
        int r = (t >> 4) + it * 16;
        int seg = t & 15;
        int grow = row0 + r;
        uint4 packed;
        if (grow < NN) {
            const float4* p = (const float4*)&x[grow * 128 + seg * 8];
            float4 f0 = p[0], f1 = p[1];
            packed.x = ((unsigned)f2bf(f0.y) << 16) | f2bf(f0.x);
            packed.y = ((unsigned)f2bf(f0.w) << 16) | f2bf(f0.z);
            packed.z = ((unsigned)f2bf(f1.y) << 16) | f2bf(f1.x);
            packed.w = ((unsigned)f2bf(f1.w) << 16) | f2bf(f1.z);
        } else {
            packed = make_uint4(0, 0, 0, 0);
        }
        *(uint4*)&xs[r * 136 + seg * 8] = packed;
    }
    __syncthreads();

    int wave = t >> 6;      // 0..3 -> Wq,Wk,Wv,Ws
    int lane = t & 63;
    int quad = lane >> 4;
    int l15  = lane & 15;
    const unsigned short* Wtm = Wt + wave * 128 * 128;

    f32x4 acc[2][8];
    #pragma unroll
    for (int mt = 0; mt < 2; ++mt)
        #pragma unroll
        for (int nt = 0; nt < 8; ++nt)
            acc[mt][nt] = (f32x4){0.f, 0.f, 0.f, 0.f};

    #pragma unroll
    for (int kk = 0; kk < 4; ++kk) {
        bf16x8 bfrag[8];
        #pragma unroll
        for (int nt = 0; nt < 8; ++nt)
            bfrag[nt] = *(const bf16x8*)&Wtm[(nt * 16 + l15) * 128 + kk * 32 + quad * 8];
        #pragma unroll
        for (int mt = 0; mt < 2; ++mt) {
            bf16x8 afrag = *(const bf16x8*)&xs[(mt * 16 + l15) * 136 + kk * 32 + quad * 8];
            #pragma unroll
            for (int nt = 0; nt < 8; ++nt)
                acc[mt][nt] = __builtin_amdgcn_mfma_f32_16x16x32_bf16(
                    afrag, bfrag[nt], acc[mt][nt], 0, 0, 0);
        }
    }

    const float* biasPtr = (wave == 0) ? bq : (wave == 1) ? bk : (wave == 2) ? bv : bs;
    float bias[8];
    #pragma unroll
    for (int nt = 0; nt < 8; ++nt) bias[nt] = biasPtr[nt * 16 + l15];

    if (wave == 0 || wave == 3) {
        float* D = (wave == 0) ? Q : S;
        #pragma unroll
        for (int mt = 0; mt < 2; ++mt)
            #pragma unroll
            for (int r = 0; r < 4; ++r) {
                int row = row0 + mt * 16 + quad * 4 + r;
                if (row < NN) {
                    #pragma unroll
                    for (int nt = 0; nt < 8; ++nt)
                        D[row * HD + nt * 16 + l15] = acc[mt][nt][r] + bias[nt];
                }
            }
    } else {
        unsigned short* D = (wave == 1) ? Kh : Vh;
        #pragma unroll
        for (int mt = 0; mt < 2; ++mt)
            #pragma unroll
            for (int r = 0; r < 4; ++r) {
                int row = row0 + mt * 16 + quad * 4 + r;
                if (row < NN) {
                    #pragma unroll
                    for (int nt = 0; nt < 8; ++nt)
                        D[row * HD + nt * 16 + l15] = f2bf(acc[mt][nt][r] + bias[nt]);
                }
            }
    }
}

// ---- CSR build: histogram of dst degrees ---------------------------------
__global__ __launch_bounds__(256) void hist_kernel(
    const int* __restrict__ ei, int* __restrict__ deg)
{
    int e = blockIdx.x * 256 + threadIdx.x;   // EE % 256 == 0
    atomicAdd(&deg[ei[EE + e]], 1);
}

// scan1: per-block (256) exclusive scan, emit block totals
__global__ __launch_bounds__(256) void scan1_kernel(
    const int* __restrict__ deg, int* __restrict__ rowptr,
    int* __restrict__ blocksum)
{
    __shared__ int s[256];
    int t = threadIdx.x;
    int g = blockIdx.x * 256 + t;
    int v = (g < NN) ? deg[g] : 0;
    s[t] = v;
    __syncthreads();
    #pragma unroll
    for (int off = 1; off < 256; off <<= 1) {
        int tmp = (t >= off) ? s[t - off] : 0;
        __syncthreads();
        s[t] += tmp;
        __syncthreads();
    }
    if (g < NN) rowptr[g] = s[t] - v;   // exclusive
    if (t == 255) blocksum[blockIdx.x] = s[255];
}

// scan2: single block scans block totals (exclusive), in place
__global__ __launch_bounds__(256) void scan2_kernel(int* __restrict__ blocksum, int nb)
{
    __shared__ int s[256];
    int t = threadIdx.x;
    int v = (t < nb) ? blocksum[t] : 0;
    s[t] = v;
    __syncthreads();
    #pragma unroll
    for (int off = 1; off < 256; off <<= 1) {
        int tmp = (t >= off) ? s[t - off] : 0;
        __syncthreads();
        s[t] += tmp;
        __syncthreads();
    }
    if (t < nb) blocksum[t] = s[t] - v;   // exclusive
}

// scan3: add block offsets
__global__ __launch_bounds__(256) void scan3_kernel(
    int* __restrict__ rowptr, const int* __restrict__ blocksum)
{
    int g = blockIdx.x * 256 + threadIdx.x;
    if (g < NN) rowptr[g] += blocksum[blockIdx.x];
}

// ---- CSR build: scatter src ids grouped by dst ---------------------------
__global__ __launch_bounds__(256) void csr_scatter_kernel(
    const int* __restrict__ ei, const int* __restrict__ rowptr,
    int* __restrict__ cursor, int* __restrict__ sortedSrc)
{
    int e = blockIdx.x * 256 + threadIdx.x;   // EE % 256 == 0
    int dst = ei[EE + e];
    int pos = atomicAdd(&cursor[dst], 1);
    sortedSrc[rowptr[dst] + pos] = ei[e];
}

// ---- Fused attention: one wave per dst (both heads), online softmax ------
__global__ __launch_bounds__(256) void attn_fused_kernel(
    const float* __restrict__ Q, const unsigned* __restrict__ Kp,
    const unsigned* __restrict__ Vp, const float* __restrict__ S,
    const int* __restrict__ rowptr, const int* __restrict__ deg,
    const int* __restrict__ sortedSrc, float* __restrict__ out)
{
    int t = threadIdx.x;
    int wave = t >> 6;
    int lane = t & 63;
    int dst = blockIdx.x * 4 + wave;      // NN % 4 == 0
    if (dst >= NN) return;

    int base = rowptr[dst];
    int cnt  = deg[dst];

    float2 q = ((const float2*)Q)[dst * 64 + lane];
    float m = -1e30f, den = 0.f, a0 = 0.f, a1 = 0.f;

    for (int c0 = 0; c0 < cnt; c0 += 64) {
        int nload = cnt - c0; if (nload > 64) nload = 64;
        int sidx = sortedSrc[base + c0 + ((lane < nload) ? lane : (nload - 1))];
        int src0 = __shfl(sidx, 0, 64);
        unsigned ku = Kp[src0 * 64 + lane];
        unsigned vu = Vp[src0 * 64 + lane];
        for (int i = 0; i < nload; ++i) {
            unsigned nku = 0, nvu = 0;
            if (i + 1 < nload) {
                int ns = __shfl(sidx, i + 1, 64);
                nku = Kp[ns * 64 + lane];
                nvu = Vp[ns * 64 + lane];
            }
            float k0 = __uint_as_float(ku << 16);
            float k1 = __uint_as_float(ku & 0xffff0000u);
            float v0 = __uint_as_float(vu << 16);
            float v1 = __uint_as_float(vu & 0xffff0000u);
            float p = fmaf(q.x, k0, q.y * k1);
            #pragma unroll
            for (int o = 16; o > 0; o >>= 1)     // reduces within each 32-half
                p += __shfl_xor(p, o, 64);
            float logit = p * 0.125f;            // / sqrt(64)
            float mnew  = fmaxf(m, logit);
            float sc    = __expf(m - mnew);
            float w     = __expf(logit - mnew);
            a0 = a0 * sc + w * v0;
            a1 = a1 * sc + w * v1;
            den = den * sc + w;
            m = mnew;
            ku = nku; vu = nvu;
        }
    }
    float inv = 1.0f / fmaxf(den, 1e-16f);
    float2 sk = ((const float2*)S)[dst * 64 + lane];
    float2 o2;
    o2.x = a0 * inv + sk.x;
    o2.y = a1 * inv + sk.y;
    ((float2*)out)[dst * 64 + lane] = o2;
}

// ---- Column stats for BN ------------------------------------------------
__global__ __launch_bounds__(256) void colstats_kernel(
    const float* __restrict__ out,
    float* __restrict__ colsum, float* __restrict__ colsq)
{
    __shared__ float ssum[256], ssq[256];
    int t = threadIdx.x;
    int c = t & 127;
    int sub = t >> 7;
    int n0 = blockIdx.x * 64;
    float ls = 0.f, lq = 0.f;
    for (int r = sub; r < 64; r += 2) {
        int n = n0 + r;
        if (n < NN) {
            float v = out[n * HD + c];
            ls += v; lq += v * v;
        }
    }
    ssum[t] = ls; ssq[t] = lq;
    __syncthreads();
    if (sub == 0) {
        atomicAdd(&colsum[c], ssum[t] + ssum[t + 128]);
        atomicAdd(&colsq[c],  ssq[t]  + ssq[t + 128]);
    }
}

// ---- BatchNorm (batch stats, biased var) + Mish, in place ----------------
__global__ __launch_bounds__(256) void bn_mish_kernel(
    float* __restrict__ y, const float* __restrict__ colsum,
    const float* __restrict__ colsq,
    const float* __restrict__ gamma, const float* __restrict__ beta)
{
    int i = blockIdx.x * 256 + threadIdx.x;
    if (i >= NN * HD) return;
    int c = i & 127;
    const float invN = 1.0f / (float)NN;
    float mean = colsum[c] * invN;
    float var  = colsq[c] * invN - mean * mean;
    float v = y[i];
    float yn = gamma[c] * (v - mean) * rsqrtf(var + BN_EPS) + beta[c];
    float sp = (yn > 20.f) ? yn : log1pf(expf(yn));
    y[i] = yn * tanhf(sp);
}

extern "C" void kernel_launch(void* const* d_in, const int* in_sizes, int n_in,
                              void* d_out, int out_size, void* d_ws, size_t ws_size,
                              hipStream_t stream) {
    const float* x     = (const float*)d_in[0];
    const int*   ei    = (const int*)d_in[1];
    const float* Wq    = (const float*)d_in[2];
    const float* bq    = (const float*)d_in[3];
    const float* Wk    = (const float*)d_in[4];
    const float* bk    = (const float*)d_in[5];
    const float* Wv    = (const float*)d_in[6];
    const float* bv    = (const float*)d_in[7];
    const float* Wsk   = (const float*)d_in[8];
    const float* bsk   = (const float*)d_in[9];
    const float* gamma = (const float*)d_in[10];
    const float* beta  = (const float*)d_in[11];
    float* out = (float*)d_out;

    char* ws = (char*)d_ws;
    float* Q  = (float*)ws;                       ws += (size_t)NN * HD * 4;
    float* S  = (float*)ws;                       ws += (size_t)NN * HD * 4;
    unsigned short* Kh = (unsigned short*)ws;     ws += (size_t)NN * HD * 2;
    unsigned short* Vh = (unsigned short*)ws;     ws += (size_t)NN * HD * 2;
    unsigned short* Wt = (unsigned short*)ws;     ws += (size_t)512 * 128 * 2;
    int* deg       = (int*)ws;                    ws += (size_t)NN * 4;
    int* rowptr    = (int*)ws;                    ws += (size_t)NN * 4;
    int* cursor    = (int*)ws;                    ws += (size_t)NN * 4;
    int* blocksum  = (int*)ws;                    ws += 256 * 4;
    int* sortedSrc = (int*)ws;                    ws += (size_t)EE * 4;
    float* colsum  = (float*)ws;                  ws += HD * 4;
    float* colsq   = (float*)ws;

    const int NB1 = (NN + 255) / 256;

    hipMemsetAsync(deg,    0, NN * sizeof(int), stream);
    hipMemsetAsync(cursor, 0, NN * sizeof(int), stream);
    hipMemsetAsync(colsum, 0, 2 * HD * sizeof(float), stream);

    wcast_kernel<<<256, 256, 0, stream>>>(Wq, Wk, Wv, Wsk, Wt);
    gemm_mfma<<<(NN + 31) / 32, 256, 0, stream>>>(x, Wt, bq, bk, bv, bsk,
                                                  Q, Kh, Vh, S);
    hist_kernel<<<EE / 256, 256, 0, stream>>>(ei, deg);
    scan1_kernel<<<NB1, 256, 0, stream>>>(deg, rowptr, blocksum);
    scan2_kernel<<<1, 256, 0, stream>>>(blocksum, NB1);
    scan3_kernel<<<NB1, 256, 0, stream>>>(rowptr, blocksum);
    csr_scatter_kernel<<<EE / 256, 256, 0, stream>>>(ei, rowptr, cursor, sortedSrc);
    attn_fused_kernel<<<NN / 4, 256, 0, stream>>>(Q, (const unsigned*)Kh,
                                                  (const unsigned*)Vh, S,
                                                  rowptr, deg, sortedSrc, out);
    colstats_kernel<<<(NN + 63) / 64, 256, 0, stream>>>(out, colsum, colsq);
    bn_mish_kernel<<<(NN * HD + 255) / 256, 256, 0, stream>>>(out, colsum, colsq,
                                                              gamma, beta);
}

// Round 5
// 301.309 us; speedup vs baseline: 3.3470x; 1.2320x over previous
//
#include <hip/hip_runtime.h>
#include <hip/hip_bf16.h>
#include <math.h>

#define NN 50000
#define EE 800000
#define HD 128   // H*D
#define BN_EPS 1e-5f

typedef __attribute__((ext_vector_type(8))) short bf16x8;
typedef __attribute__((ext_vector_type(4))) float f32x4;

__device__ __forceinline__ unsigned short f2bf(float f) {
    // round-to-nearest-even bf16
    unsigned u = __float_as_uint(f);
    unsigned rounded = u + 0x7fffu + ((u >> 16) & 1u);
    return (unsigned short)(rounded >> 16);
}
__device__ __forceinline__ float bflo(unsigned u) { return __uint_as_float(u << 16); }
__device__ __forceinline__ float bfhi(unsigned u) { return __uint_as_float(u & 0xffff0000u); }

// ---- Prep: Wt[n][k] = bf16(W_{n/128}[k][n%128]) ; n in [0,512) ----------
__global__ __launch_bounds__(256) void wcast_kernel(
    const float* __restrict__ Wq, const float* __restrict__ Wk,
    const float* __restrict__ Wv, const float* __restrict__ Ws,
    unsigned short* __restrict__ Wt)
{
    int i = blockIdx.x * 256 + threadIdx.x;   // 65536 total
    int n = i >> 7;
    int k = i & 127;
    const float* W = (n < 128) ? Wq : (n < 256) ? Wk : (n < 384) ? Wv : Ws;
    Wt[n * 128 + k] = f2bf(W[k * 128 + (n & 127)]);
}

// ---- Phase 1: MFMA GEMM. Block = 32 rows x 512 cols; wave w owns matrix w.
// All four outputs stored bf16.
__global__ __launch_bounds__(256) void gemm_mfma(
    const float* __restrict__ x, const unsigned short* __restrict__ Wt,
    const float* __restrict__ bq, const float* __restrict__ bk,
    const float* __restrict__ bv, const float* __restrict__ bs,
    unsigned short* __restrict__ Qh, unsigned short* __restrict__ Kh,
    unsigned short* __restrict__ Vh, unsigned short* __restrict__ Sh)
{
    // row stride 136 bf16 = 272B: 16B-aligned, breaks 16-way bank aliasing
    __shared__ __align__(16) unsigned short xs[32 * 136];
    int t = threadIdx.x;
    int row0 = blockIdx.x * 32;

    // stage + cast x tile (32x128 fp32 -> bf16 LDS)
    #pragma unroll
    for (int it = 0; it < 2; ++it) {
        int r = (t >> 4) + it * 16;
        int seg = t & 15;
        int grow = row0 + r;
        uint4 packed;
        if (grow < NN) {
            const float4* p = (const float4*)&x[grow * 128 + seg * 8];
            float4 f0 = p[0], f1 = p[1];
            packed.x = ((unsigned)f2bf(f0.y) << 16) | f2bf(f0.x);
            packed.y = ((unsigned)f2bf(f0.w) << 16) | f2bf(f0.z);
            packed.z = ((unsigned)f2bf(f1.y) << 16) | f2bf(f1.x);
            packed.w = ((unsigned)f2bf(f1.w) << 16) | f2bf(f1.z);
        } else {
            packed = make_uint4(0, 0, 0, 0);
        }
        *(uint4*)&xs[r * 136 + seg * 8] = packed;
    }
    __syncthreads();

    int wave = t >> 6;      // 0..3 -> Wq,Wk,Wv,Ws
    int lane = t & 63;
    int quad = lane >> 4;
    int l15  = lane & 15;
    const unsigned short* Wtm = Wt + wave * 128 * 128;

    f32x4 acc[2][8];
    #pragma unroll
    for (int mt = 0; mt < 2; ++mt)
        #pragma unroll
        for (int nt = 0; nt < 8; ++nt)
            acc[mt][nt] = (f32x4){0.f, 0.f, 0.f, 0.f};

    #pragma unroll
    for (int kk = 0; kk < 4; ++kk) {
        bf16x8 bfrag[8];
        #pragma unroll
        for (int nt = 0; nt < 8; ++nt)
            bfrag[nt] = *(const bf16x8*)&Wtm[(nt * 16 + l15) * 128 + kk * 32 + quad * 8];
        #pragma unroll
        for (int mt = 0; mt < 2; ++mt) {
            bf16x8 afrag = *(const bf16x8*)&xs[(mt * 16 + l15) * 136 + kk * 32 + quad * 8];
            #pragma unroll
            for (int nt = 0; nt < 8; ++nt)
                acc[mt][nt] = __builtin_amdgcn_mfma_f32_16x16x32_bf16(
                    afrag, bfrag[nt], acc[mt][nt], 0, 0, 0);
        }
    }

    const float* biasPtr = (wave == 0) ? bq : (wave == 1) ? bk : (wave == 2) ? bv : bs;
    unsigned short* D = (wave == 0) ? Qh : (wave == 1) ? Kh : (wave == 2) ? Vh : Sh;
    float bias[8];
    #pragma unroll
    for (int nt = 0; nt < 8; ++nt) bias[nt] = biasPtr[nt * 16 + l15];

    #pragma unroll
    for (int mt = 0; mt < 2; ++mt)
        #pragma unroll
        for (int r = 0; r < 4; ++r) {
            int row = row0 + mt * 16 + quad * 4 + r;
            if (row < NN) {
                #pragma unroll
                for (int nt = 0; nt < 8; ++nt)
                    D[row * HD + nt * 16 + l15] = f2bf(acc[mt][nt][r] + bias[nt]);
            }
        }
}

// ---- CSR: histogram + per-edge rank in ONE atomic pass -------------------
__global__ __launch_bounds__(256) void csr_pos_kernel(
    const int* __restrict__ ei, int* __restrict__ deg, int* __restrict__ pos)
{
    int e = blockIdx.x * 256 + threadIdx.x;   // EE % 256 == 0
    pos[e] = atomicAdd(&deg[ei[EE + e]], 1);
}

// scan1: per-block (256) exclusive scan of deg, emit block totals
__global__ __launch_bounds__(256) void scan1_kernel(
    const int* __restrict__ deg, int* __restrict__ rowptr,
    int* __restrict__ blocksum)
{
    __shared__ int s[256];
    int t = threadIdx.x;
    int g = blockIdx.x * 256 + t;
    int v = (g < NN) ? deg[g] : 0;
    s[t] = v;
    __syncthreads();
    #pragma unroll
    for (int off = 1; off < 256; off <<= 1) {
        int tmp = (t >= off) ? s[t - off] : 0;
        __syncthreads();
        s[t] += tmp;
        __syncthreads();
    }
    if (g < NN) rowptr[g] = s[t] - v;   // block-local exclusive
    if (t == 255) blocksum[blockIdx.x] = s[255];
}

// scan2: single block scans block totals (exclusive) in place; also zeros
// the 256 floats of colsum||colsq.
__global__ __launch_bounds__(256) void scan2_kernel(
    int* __restrict__ blocksum, int nb, float* __restrict__ colzero)
{
    __shared__ int s[256];
    int t = threadIdx.x;
    colzero[t] = 0.f;
    int v = (t < nb) ? blocksum[t] : 0;
    s[t] = v;
    __syncthreads();
    #pragma unroll
    for (int off = 1; off < 256; off <<= 1) {
        int tmp = (t >= off) ? s[t - off] : 0;
        __syncthreads();
        s[t] += tmp;
        __syncthreads();
    }
    if (t < nb) blocksum[t] = s[t] - v;   // exclusive
}

// ---- CSR: scatter src ids grouped by dst (rank precomputed) --------------
__global__ __launch_bounds__(256) void csr_scatter_kernel(
    const int* __restrict__ ei, const int* __restrict__ rowptr,
    const int* __restrict__ blocksum, const int* __restrict__ pos,
    int* __restrict__ sortedSrc)
{
    int e = blockIdx.x * 256 + threadIdx.x;   // EE % 256 == 0
    int dst = ei[EE + e];
    sortedSrc[rowptr[dst] + blocksum[dst >> 8] + pos[e]] = ei[e];
}

// ---- Fused attention: one wave per dst; 2 edges per iteration ------------
// Lanes 0-31 = edge i, lanes 32-63 = edge i+1. Each lane: 4 dims (uint2 bf16).
// Head of lane = (sub>>4). Dot-reduce = 4 shfl_xor within 16-lane groups.
// Two online-softmax states merged across halves at the end.
__global__ __launch_bounds__(256) void attn_fused_kernel(
    const uint2* __restrict__ Qp, const uint2* __restrict__ Kp,
    const uint2* __restrict__ Vp, const uint2* __restrict__ Sp,
    const int* __restrict__ rowptr, const int* __restrict__ blocksum,
    const int* __restrict__ deg, const int* __restrict__ sortedSrc,
    float* __restrict__ out)
{
    int t = threadIdx.x;
    int wave = t >> 6;
    int lane = t & 63;
    int sub  = lane & 31;
    int half = lane >> 5;
    int dst = blockIdx.x * 4 + wave;      // NN % 4 == 0

    int base = rowptr[dst] + blocksum[dst >> 8];
    int cnt  = deg[dst];

    uint2 qu = Qp[dst * 32 + sub];
    float q0 = bflo(qu.x), q1 = bfhi(qu.x), q2 = bflo(qu.y), q3 = bfhi(qu.y);

    float m = -1e30f, den = 0.f;
    float a0 = 0.f, a1 = 0.f, a2 = 0.f, a3 = 0.f;

    for (int c0 = 0; c0 < cnt; c0 += 64) {
        int nload = cnt - c0; if (nload > 64) nload = 64;
        int ll = lane < (nload - 1) ? lane : (nload - 1);
        int sidx = sortedSrc[base + c0 + ll];
        int npair = (nload + 1) >> 1;

        int j = half;
        int s0 = __shfl(sidx, j, 64);
        uint2 ku = Kp[s0 * 32 + sub];
        uint2 vu = Vp[s0 * 32 + sub];
        bool valid = (j < nload);

        for (int i = 0; i < npair; ++i) {
            uint2 nku = ku, nvu = vu;
            bool nvalid = false;
            if (i + 1 < npair) {
                int jn = (i + 1) * 2 + half;      // always <= 63 here
                int sn = __shfl(sidx, jn, 64);
                nvalid = (jn < nload);
                nku = Kp[sn * 32 + sub];
                nvu = Vp[sn * 32 + sub];
            }
            float k0 = bflo(ku.x), k1 = bfhi(ku.x), k2 = bflo(ku.y), k3 = bfhi(ku.y);
            float p = fmaf(q0, k0, fmaf(q1, k1, fmaf(q2, k2, q3 * k3)));
            p += __shfl_xor(p, 1, 64);
            p += __shfl_xor(p, 2, 64);
            p += __shfl_xor(p, 4, 64);
            p += __shfl_xor(p, 8, 64);
            float logit = p * 0.125f;             // / sqrt(64)
            float mnew  = valid ? fmaxf(m, logit) : m;
            float sc    = __expf(m - mnew);
            float w     = valid ? __expf(logit - mnew) : 0.f;
            float v0 = bflo(vu.x), v1 = bfhi(vu.x), v2 = bflo(vu.y), v3 = bfhi(vu.y);
            a0 = fmaf(a0, sc, w * v0);
            a1 = fmaf(a1, sc, w * v1);
            a2 = fmaf(a2, sc, w * v2);
            a3 = fmaf(a3, sc, w * v3);
            den = fmaf(den, sc, w);
            m = mnew;
            ku = nku; vu = nvu; valid = nvalid;
        }
    }

    // merge the two halves' online-softmax states
    float mo  = __shfl_xor(m, 32, 64);
    float dno = __shfl_xor(den, 32, 64);
    float b0  = __shfl_xor(a0, 32, 64);
    float b1  = __shfl_xor(a1, 32, 64);
    float b2  = __shfl_xor(a2, 32, 64);
    float b3  = __shfl_xor(a3, 32, 64);
    float M   = fmaxf(m, mo);
    float ss  = __expf(m - M);
    float so  = __expf(mo - M);
    float dt  = den * ss + dno * so;
    float inv = 1.0f / fmaxf(dt, 1e-16f);

    if (half == 0) {
        uint2 sk = Sp[dst * 32 + sub];
        float4 o;
        o.x = fmaf(a0, ss, b0 * so) * inv + bflo(sk.x);
        o.y = fmaf(a1, ss, b1 * so) * inv + bfhi(sk.x);
        o.z = fmaf(a2, ss, b2 * so) * inv + bflo(sk.y);
        o.w = fmaf(a3, ss, b3 * so) * inv + bfhi(sk.y);
        ((float4*)out)[dst * 32 + sub] = o;
    }
}

// ---- Column stats for BN ------------------------------------------------
__global__ __launch_bounds__(256) void colstats_kernel(
    const float* __restrict__ out,
    float* __restrict__ colsum, float* __restrict__ colsq)
{
    __shared__ float ssum[256], ssq[256];
    int t = threadIdx.x;
    int c = t & 127;
    int sub = t >> 7;
    int n0 = blockIdx.x * 64;
    float ls = 0.f, lq = 0.f;
    for (int r = sub; r < 64; r += 2) {
        int n = n0 + r;
        if (n < NN) {
            float v = out[n * HD + c];
            ls += v; lq += v * v;
        }
    }
    ssum[t] = ls; ssq[t] = lq;
    __syncthreads();
    if (sub == 0) {
        atomicAdd(&colsum[c], ssum[t] + ssum[t + 128]);
        atomicAdd(&colsq[c],  ssq[t]  + ssq[t + 128]);
    }
}

// ---- BatchNorm (batch stats, biased var) + Mish, in place ----------------
__global__ __launch_bounds__(256) void bn_mish_kernel(
    float* __restrict__ y, const float* __restrict__ colsum,
    const float* __restrict__ colsq,
    const float* __restrict__ gamma, const float* __restrict__ beta)
{
    int i = blockIdx.x * 256 + threadIdx.x;
    if (i >= NN * HD) return;
    int c = i & 127;
    const float invN = 1.0f / (float)NN;
    float mean = colsum[c] * invN;
    float var  = colsq[c] * invN - mean * mean;
    float v = y[i];
    float yn = gamma[c] * (v - mean) * rsqrtf(var + BN_EPS) + beta[c];
    float sp = (yn > 20.f) ? yn : log1pf(expf(yn));
    y[i] = yn * tanhf(sp);
}

extern "C" void kernel_launch(void* const* d_in, const int* in_sizes, int n_in,
                              void* d_out, int out_size, void* d_ws, size_t ws_size,
                              hipStream_t stream) {
    const float* x     = (const float*)d_in[0];
    const int*   ei    = (const int*)d_in[1];
    const float* Wq    = (const float*)d_in[2];
    const float* bq    = (const float*)d_in[3];
    const float* Wk    = (const float*)d_in[4];
    const float* bk    = (const float*)d_in[5];
    const float* Wv    = (const float*)d_in[6];
    const float* bv    = (const float*)d_in[7];
    const float* Wsk   = (const float*)d_in[8];
    const float* bsk   = (const float*)d_in[9];
    const float* gamma = (const float*)d_in[10];
    const float* beta  = (const float*)d_in[11];
    float* out = (float*)d_out;

    char* ws = (char*)d_ws;
    unsigned short* Qh = (unsigned short*)ws;     ws += (size_t)NN * HD * 2;
    unsigned short* Kh = (unsigned short*)ws;     ws += (size_t)NN * HD * 2;
    unsigned short* Vh = (unsigned short*)ws;     ws += (size_t)NN * HD * 2;
    unsigned short* Sh = (unsigned short*)ws;     ws += (size_t)NN * HD * 2;
    unsigned short* Wt = (unsigned short*)ws;     ws += (size_t)512 * 128 * 2;
    int* deg       = (int*)ws;                    ws += (size_t)NN * 4;
    int* rowptr    = (int*)ws;                    ws += (size_t)NN * 4;
    int* blocksum  = (int*)ws;                    ws += 256 * 4;
    int* pos       = (int*)ws;                    ws += (size_t)EE * 4;
    int* sortedSrc = (int*)ws;                    ws += (size_t)EE * 4;
    float* colsum  = (float*)ws;                  ws += HD * 4;
    float* colsq   = (float*)ws;

    const int NB1 = (NN + 255) / 256;

    hipMemsetAsync(deg, 0, NN * sizeof(int), stream);

    wcast_kernel<<<256, 256, 0, stream>>>(Wq, Wk, Wv, Wsk, Wt);
    gemm_mfma<<<(NN + 31) / 32, 256, 0, stream>>>(x, Wt, bq, bk, bv, bsk,
                                                  Qh, Kh, Vh, Sh);
    csr_pos_kernel<<<EE / 256, 256, 0, stream>>>(ei, deg, pos);
    scan1_kernel<<<NB1, 256, 0, stream>>>(deg, rowptr, blocksum);
    scan2_kernel<<<1, 256, 0, stream>>>(blocksum, NB1, colsum);
    csr_scatter_kernel<<<EE / 256, 256, 0, stream>>>(ei, rowptr, blocksum, pos,
                                                     sortedSrc);
    attn_fused_kernel<<<NN / 4, 256, 0, stream>>>(
        (const uint2*)Qh, (const uint2*)Kh, (const uint2*)Vh, (const uint2*)Sh,
        rowptr, blocksum, deg, sortedSrc, out);
    colstats_kernel<<<(NN + 63) / 64, 256, 0, stream>>>(out, colsum, colsq);
    bn_mish_kernel<<<(NN * HD + 255) / 256, 256, 0, stream>>>(out, colsum, colsq,
                                                              gamma, beta);
}